// Round 2
// baseline (1196.758 us; speedup 1.0000x reference)
//
#include <hip/hip_runtime.h>
#include <math.h>

// Problem constants (B=2, H=W=48, C=E=256, NH=8, GH=1)
#define NTOK 2304              // H*W
#define NS   4608              // B*NTOK
#define CH   256               // C == E == E*GH
#define NHEAD 8
#define DH   32

// ---------------- LayerNorm kernels ----------------

// LN over channel dim while transposing [B,C,N] -> [Ns, C]
__global__ __launch_bounds__(256) void k_ln_tok(const float* __restrict__ x,
    const float* __restrict__ g, const float* __restrict__ be, float* __restrict__ out)
{
    int row = blockIdx.x;              // b*NTOK + n
    int b = row / NTOK, n = row - b * NTOK;
    int c = threadIdx.x;
    float v = x[((size_t)b * CH + c) * NTOK + n];
    __shared__ float s1[256], s2[256];
    s1[c] = v; s2[c] = v * v;
    __syncthreads();
    #pragma unroll
    for (int st = 128; st > 0; st >>= 1) {
        if (c < st) { s1[c] += s1[c + st]; s2[c] += s2[c + st]; }
        __syncthreads();
    }
    float mu = s1[0] * (1.f / CH);
    float var = s2[0] * (1.f / CH) - mu * mu;
    float r = rsqrtf(var + 1e-5f);
    out[(size_t)row * CH + c] = (v - mu) * r * g[c] + be[c];
}

// plain LN: fp32 [NS,256] -> fp32 [NS,256]
__global__ __launch_bounds__(256) void k_ln(const float* __restrict__ in,
    const float* __restrict__ g, const float* __restrict__ be, float* __restrict__ out)
{
    int row = blockIdx.x;
    int c = threadIdx.x;
    float v = in[(size_t)row * CH + c];
    __shared__ float s1[256], s2[256];
    s1[c] = v; s2[c] = v * v;
    __syncthreads();
    #pragma unroll
    for (int st = 128; st > 0; st >>= 1) {
        if (c < st) { s1[c] += s1[c + st]; s2[c] += s2[c + st]; }
        __syncthreads();
    }
    float mu = s1[0] * (1.f / CH);
    float var = s2[0] * (1.f / CH) - mu * mu;
    float r = rsqrtf(var + 1e-5f);
    out[(size_t)row * CH + c] = (v - mu) * r * g[c] + be[c];
}

// final LN + transpose to [B, E, H*W]
__global__ __launch_bounds__(256) void k_ln_out(const float* __restrict__ in,
    const float* __restrict__ g, const float* __restrict__ be, float* __restrict__ out)
{
    int row = blockIdx.x;
    int b = row / NTOK, n = row - b * NTOK;
    int c = threadIdx.x;
    float v = in[(size_t)row * CH + c];
    __shared__ float s1[256], s2[256];
    s1[c] = v; s2[c] = v * v;
    __syncthreads();
    #pragma unroll
    for (int st = 128; st > 0; st >>= 1) {
        if (c < st) { s1[c] += s1[c + st]; s2[c] += s2[c + st]; }
        __syncthreads();
    }
    float mu = s1[0] * (1.f / CH);
    float var = s2[0] * (1.f / CH) - mu * mu;
    float r = rsqrtf(var + 1e-5f);
    float val = (v - mu) * r * g[c] + be[c];
    out[((size_t)b * CH + c) * NTOK + n] = val;
}

// ---------------- GEMM: out = act(A[M,256] @ W[256,256] + bias (+resid)) ----------------
// ACT: 0 = none, 1 = exact gelu
template<int ACT>
__global__ __launch_bounds__(256) void k_gemm(const float* __restrict__ A,
    const float* __restrict__ W, const float* __restrict__ bias,
    const float* __restrict__ resid, float* __restrict__ out)
{
    __shared__ float As[16][68];   // [k][m], padded
    __shared__ float Bs[16][64];   // [k][n]
    int t = threadIdx.x;
    int bm = blockIdx.x * 64;
    int bn = blockIdx.y * 64;
    int tm = (t >> 4) * 4;
    int tc = (t & 15) * 4;
    int ar = t >> 2, ac4 = (t & 3) * 4;
    int br = t >> 4, bc4 = (t & 15) * 4;
    float acc[4][4];
    #pragma unroll
    for (int i = 0; i < 4; i++)
        #pragma unroll
        for (int j = 0; j < 4; j++) acc[i][j] = 0.f;

    for (int kk = 0; kk < 256; kk += 16) {
        float4 av = *(const float4*)&A[(size_t)(bm + ar) * 256 + kk + ac4];
        As[ac4 + 0][ar] = av.x; As[ac4 + 1][ar] = av.y;
        As[ac4 + 2][ar] = av.z; As[ac4 + 3][ar] = av.w;
        float4 bv = *(const float4*)&W[(size_t)(kk + br) * 256 + bn + bc4];
        *(float4*)&Bs[br][bc4] = bv;
        __syncthreads();
        #pragma unroll
        for (int k = 0; k < 16; k++) {
            float4 a4 = *(const float4*)&As[k][tm];
            float4 b4 = *(const float4*)&Bs[k][tc];
            acc[0][0] += a4.x * b4.x; acc[0][1] += a4.x * b4.y; acc[0][2] += a4.x * b4.z; acc[0][3] += a4.x * b4.w;
            acc[1][0] += a4.y * b4.x; acc[1][1] += a4.y * b4.y; acc[1][2] += a4.y * b4.z; acc[1][3] += a4.y * b4.w;
            acc[2][0] += a4.z * b4.x; acc[2][1] += a4.z * b4.y; acc[2][2] += a4.z * b4.z; acc[2][3] += a4.z * b4.w;
            acc[3][0] += a4.w * b4.x; acc[3][1] += a4.w * b4.y; acc[3][2] += a4.w * b4.z; acc[3][3] += a4.w * b4.w;
        }
        __syncthreads();
    }
    #pragma unroll
    for (int i = 0; i < 4; i++) {
        int row = bm + tm + i;
        float4 o4;
        float* pv = (float*)&o4;
        #pragma unroll
        for (int j = 0; j < 4; j++) {
            int col = bn + tc + j;
            float vv = acc[i][j];
            if (bias)  vv += bias[col];
            if (resid) vv += resid[(size_t)row * 256 + col];
            if (ACT == 1) vv = 0.5f * vv * (1.f + erff(vv * 0.70710678118654752f));
            pv[j] = vv;
        }
        *(float4*)&out[(size_t)row * 256 + bn + tc] = o4;
    }
}

// ---------------- Attention: flash, tiled online softmax ----------------
// one query per lane, split-K across the 4 waves, 16-key tiles for ILP:
// scores for the whole tile first (16 independent dot chains), single
// rescale of acc per tile (amortizes 32 FMA/key -> 2 FMA/key), then PV.
#define KT 16

__global__ __launch_bounds__(256) void k_attn(const float* __restrict__ Q,
    const float* __restrict__ K, const float* __restrict__ V, float* __restrict__ O)
{
    int bh = blockIdx.y;
    int b = bh >> 3, h = bh & 7;
    int lane = threadIdx.x & 63;
    int w = threadIdx.x >> 6;
    int qi = blockIdx.x * 64 + lane;   // 36*64 = 2304, always in range
    size_t headoff = (size_t)b * NTOK * 256 + h * 32;

    float qr[32];
    const float* qp = Q + headoff + (size_t)qi * 256;
    #pragma unroll
    for (int d0 = 0; d0 < 32; d0 += 4) {
        float4 t4 = *(const float4*)(qp + d0);
        qr[d0] = t4.x; qr[d0 + 1] = t4.y; qr[d0 + 2] = t4.z; qr[d0 + 3] = t4.w;
    }
    const float scale = 0.17677669529663687f;   // 1/sqrt(32)
    #pragma unroll
    for (int d = 0; d < 32; d++) qr[d] *= scale; // fold scale into q

    float m = -1e30f, l = 0.f;
    float acc[32];
    #pragma unroll
    for (int d = 0; d < 32; d++) acc[d] = 0.f;

    const float* kbase = K + headoff;
    const float* vbase = V + headoff;
    int k0 = w * (NTOK / 4);

    for (int kt = 0; kt < NTOK / 4; kt += KT) {
        // 1) tile scores — 16 independent dot-product chains (ILP)
        float s[KT];
        #pragma unroll
        for (int j = 0; j < KT; j++) {
            const float* kp = kbase + (size_t)(k0 + kt + j) * 256;
            float sj = 0.f;
            #pragma unroll
            for (int d0 = 0; d0 < 32; d0 += 4) {
                float4 kv = *(const float4*)(kp + d0);
                sj += qr[d0] * kv.x + qr[d0 + 1] * kv.y
                    + qr[d0 + 2] * kv.z + qr[d0 + 3] * kv.w;
            }
            s[j] = sj;
        }
        // 2) tile max + single rescale
        float mt = s[0];
        #pragma unroll
        for (int j = 1; j < KT; j++) mt = fmaxf(mt, s[j]);
        float mn = fmaxf(m, mt);
        float corr = __expf(m - mn);
        m = mn;
        float p[KT]; float ls = 0.f;
        #pragma unroll
        for (int j = 0; j < KT; j++) { p[j] = __expf(s[j] - mn); ls += p[j]; }
        l = l * corr + ls;
        #pragma unroll
        for (int d = 0; d < 32; d++) acc[d] *= corr;
        // 3) PV — 32 independent accumulation chains across d
        #pragma unroll
        for (int j = 0; j < KT; j++) {
            const float* vp = vbase + (size_t)(k0 + kt + j) * 256;
            #pragma unroll
            for (int d0 = 0; d0 < 32; d0 += 4) {
                float4 vv = *(const float4*)(vp + d0);
                acc[d0]     += p[j] * vv.x;
                acc[d0 + 1] += p[j] * vv.y;
                acc[d0 + 2] += p[j] * vv.z;
                acc[d0 + 3] += p[j] * vv.w;
            }
        }
    }

    // merge the 4 split-K partials via LDS
    __shared__ float sm[4][64], sl[4][64];
    __shared__ float sacc[4][64][33];
    sm[w][lane] = m; sl[w][lane] = l;
    #pragma unroll
    for (int d = 0; d < 32; d++) sacc[w][lane][d] = acc[d];
    __syncthreads();

    if (threadIdx.x < 64) {
        int tq = threadIdx.x;
        int q2 = blockIdx.x * 64 + tq;
        float M = fmaxf(fmaxf(sm[0][tq], sm[1][tq]), fmaxf(sm[2][tq], sm[3][tq]));
        float wgt[4]; float L = 0.f;
        #pragma unroll
        for (int s = 0; s < 4; s++) { wgt[s] = __expf(sm[s][tq] - M); L += sl[s][tq] * wgt[s]; }
        float invL = 1.f / L;
        float* op = O + headoff + (size_t)q2 * 256;
        #pragma unroll
        for (int d = 0; d < 32; d++) {
            float od = sacc[0][tq][d] * wgt[0] + sacc[1][tq][d] * wgt[1]
                     + sacc[2][tq][d] * wgt[2] + sacc[3][tq][d] * wgt[3];
            op[d] = od * invL;
        }
    }
}

// ---------------- GAT pieces ----------------

// a_src[i] = sum_d h[i,d]*att_src[d]; a_dst likewise
__global__ __launch_bounds__(256) void k_attvec(const float* __restrict__ h,
    const float* __restrict__ wsrc, const float* __restrict__ wdst,
    float* __restrict__ a_src, float* __restrict__ a_dst)
{
    int node = blockIdx.x;
    int c = threadIdx.x;
    float hv = h[(size_t)node * CH + c];
    __shared__ float s1[256], s2[256];
    s1[c] = hv * wsrc[c]; s2[c] = hv * wdst[c];
    __syncthreads();
    #pragma unroll
    for (int st = 128; st > 0; st >>= 1) {
        if (c < st) { s1[c] += s1[c + st]; s2[c] += s2[c + st]; }
        __syncthreads();
    }
    if (c == 0) { a_src[node] = s1[0]; a_dst[node] = s2[0]; }
}

// build fixed-stride CSR (max degree on this grid graph is 9, slot=16)
__global__ void k_fill_edges(const int* __restrict__ ei, int Eed,
    int* __restrict__ deg, int* __restrict__ csr)
{
    int e = blockIdx.x * 256 + threadIdx.x;
    if (e >= Eed) return;
    int src = ei[e];
    int dst = ei[Eed + e];
    int pos = atomicAdd(&deg[dst], 1);
    if (pos < 16) csr[dst * 16 + pos] = src;
}

// per-dst edge softmax + aggregation + elu + residual (writes nf in place)
__global__ __launch_bounds__(256) void k_gat_agg(const int* __restrict__ deg,
    const int* __restrict__ csr, const float* __restrict__ a_src,
    const float* __restrict__ a_dst, const float* __restrict__ h,
    const float* __restrict__ gbias, float* __restrict__ nf)
{
    int dst = blockIdx.x;
    int t = threadIdx.x;
    __shared__ float logit[16];
    __shared__ float alpha[16];
    __shared__ int srcs[16];
    int cnt = deg[dst]; if (cnt > 16) cnt = 16;
    if (t < cnt) {
        int s = csr[dst * 16 + t];
        srcs[t] = s;
        float lg = a_src[s] + a_dst[dst];
        logit[t] = lg > 0.f ? lg : 0.2f * lg;
    }
    __syncthreads();
    if (t == 0) {
        float mx = -1e30f;
        for (int i = 0; i < cnt; i++) mx = fmaxf(mx, logit[i]);
        float dn = 0.f;
        for (int i = 0; i < cnt; i++) { float ex = __expf(logit[i] - mx); alpha[i] = ex; dn += ex; }
        float inv = 1.f / (dn + 1e-16f);
        for (int i = 0; i < cnt; i++) alpha[i] *= inv;
    }
    __syncthreads();
    float accv = 0.f;
    for (int i = 0; i < cnt; i++) accv += alpha[i] * h[(size_t)srcs[i] * CH + t];
    float val = accv + gbias[t];
    val = val > 0.f ? val : expm1f(val);
    nf[(size_t)dst * CH + t] += val;
}

// ---------------- orchestration ----------------
extern "C" void kernel_launch(void* const* d_in, const int* in_sizes, int n_in,
                              void* d_out, int out_size, void* d_ws, size_t ws_size,
                              hipStream_t stream)
{
    const float* x_cnn   = (const float*)d_in[0];
    const int*   edge    = (const int*)d_in[1];
    const float* norm1_g = (const float*)d_in[2];
    const float* norm1_b = (const float*)d_in[3];
    const float* proj_w  = (const float*)d_in[4];
    const float* proj_b  = (const float*)d_in[5];
    const float* wq      = (const float*)d_in[6];
    const float* bq      = (const float*)d_in[7];
    const float* wk      = (const float*)d_in[8];
    const float* bk      = (const float*)d_in[9];
    const float* wv      = (const float*)d_in[10];
    const float* bv      = (const float*)d_in[11];
    const float* wo      = (const float*)d_in[12];
    const float* bo      = (const float*)d_in[13];
    const float* norm2_g = (const float*)d_in[14];
    const float* norm2_b = (const float*)d_in[15];
    const float* gpl_w   = (const float*)d_in[16];
    const float* gpl_b   = (const float*)d_in[17];
    const float* gat_w   = (const float*)d_in[18];
    const float* att_src = (const float*)d_in[19];
    const float* att_dst = (const float*)d_in[20];
    const float* gat_bias= (const float*)d_in[21];
    const float* norm3_g = (const float*)d_in[22];
    const float* norm3_b = (const float*)d_in[23];
    const float* mlp_w1  = (const float*)d_in[24];
    const float* mlp_b1  = (const float*)d_in[25];
    const float* mlp_w2  = (const float*)d_in[26];
    const float* mlp_b2  = (const float*)d_in[27];
    const float* fn_g    = (const float*)d_in[28];
    const float* fn_b    = (const float*)d_in[29];

    int Eed = in_sizes[1] / 2;
    float* out = (float*)d_out;

    const size_t NB = (size_t)NS * CH;   // 1,179,648 floats per buffer
    float* ws   = (float*)d_ws;
    float* bufA = ws + 0 * NB;
    float* bufB = ws + 1 * NB;
    float* bufC = ws + 2 * NB;
    float* bufD = ws + 3 * NB;
    float* bufE = ws + 4 * NB;
    float* a_src = ws + 5 * NB;
    float* a_dst = a_src + NS;
    int*   deg   = (int*)(a_dst + NS);
    int*   csr   = deg + NS;             // NS*16 ints
    // total ws use: 5*4.72MB + ~0.35MB ≈ 24 MB

    dim3 g72(72, 4);

    // 1. tokenize + LN1 -> bufA
    k_ln_tok<<<NS, 256, 0, stream>>>(x_cnn, norm1_g, norm1_b, bufA);
    // 2. xv = bufA @ proj + proj_b -> bufB
    k_gemm<0><<<g72, 256, 0, stream>>>(bufA, proj_w, proj_b, nullptr, bufB);
    // 3. q,k,v
    k_gemm<0><<<g72, 256, 0, stream>>>(bufB, wq, bq, nullptr, bufC);
    k_gemm<0><<<g72, 256, 0, stream>>>(bufB, wk, bk, nullptr, bufD);
    k_gemm<0><<<g72, 256, 0, stream>>>(bufB, wv, bv, nullptr, bufE);
    // 4. attention -> bufA
    k_attn<<<dim3(36, 16), 256, 0, stream>>>(bufC, bufD, bufE, bufA);
    // 5. nf = bufB + bufA @ wo + bo  (in-place into bufB)
    k_gemm<0><<<g72, 256, 0, stream>>>(bufA, wo, bo, bufB, bufB);
    // 6. ln2 -> bufC
    k_ln<<<NS, 256, 0, stream>>>(bufB, norm2_g, norm2_b, bufC);
    // 7. xg = bufC @ gpl_w + gpl_b -> bufD
    k_gemm<0><<<g72, 256, 0, stream>>>(bufC, gpl_w, gpl_b, nullptr, bufD);
    // 8. h = bufD @ gat_w -> bufE
    k_gemm<0><<<g72, 256, 0, stream>>>(bufD, gat_w, nullptr, nullptr, bufE);
    // 9. a_src/a_dst
    k_attvec<<<NS, 256, 0, stream>>>(bufE, att_src, att_dst, a_src, a_dst);
    // 10. CSR build
    hipMemsetAsync(deg, 0, NS * sizeof(int), stream);
    k_fill_edges<<<(Eed + 255) / 256, 256, 0, stream>>>(edge, Eed, deg, csr);
    // 11. GAT aggregate + elu + residual (bufB updated in place)
    k_gat_agg<<<NS, 256, 0, stream>>>(deg, csr, a_src, a_dst, bufE, gat_bias, bufB);
    // 12. ln3 -> bufC
    k_ln<<<NS, 256, 0, stream>>>(bufB, norm3_g, norm3_b, bufC);
    // 13. mlp1 = gelu(bufC @ mlp_w1 + b1) -> bufD
    k_gemm<1><<<g72, 256, 0, stream>>>(bufC, mlp_w1, mlp_b1, nullptr, bufD);
    // 14. y_pre = bufC + bufD @ mlp_w2 + b2 -> bufA
    k_gemm<0><<<g72, 256, 0, stream>>>(bufD, mlp_w2, mlp_b2, bufC, bufA);
    // 15. final LN + transpose -> out
    k_ln_out<<<NS, 256, 0, stream>>>(bufA, fn_g, fn_b, out);
}

// Round 3
// 292.657 us; speedup vs baseline: 4.0893x; 4.0893x over previous
//
#include <hip/hip_runtime.h>
#include <math.h>

// Problem constants (B=2, H=W=48, C=E=256, NH=8, GH=1)
#define NTOK 2304              // H*W
#define NS   4608              // B*NTOK
#define CH   256               // C == E == E*GH
#define NHEAD 8
#define DH   32

using bf16x8 = __attribute__((ext_vector_type(8))) short;
using f32x4  = __attribute__((ext_vector_type(4))) float;

__device__ __forceinline__ unsigned short f2bf(float x) {
    unsigned int u = __float_as_uint(x);
    u = (u + 0x7fffu + ((u >> 16) & 1u)) >> 16;   // RNE
    return (unsigned short)u;
}

// ---------------- LayerNorm kernels ----------------

__global__ __launch_bounds__(256) void k_ln_tok(const float* __restrict__ x,
    const float* __restrict__ g, const float* __restrict__ be, float* __restrict__ out)
{
    int row = blockIdx.x;              // b*NTOK + n
    int b = row / NTOK, n = row - b * NTOK;
    int c = threadIdx.x;
    float v = x[((size_t)b * CH + c) * NTOK + n];
    __shared__ float s1[256], s2[256];
    s1[c] = v; s2[c] = v * v;
    __syncthreads();
    #pragma unroll
    for (int st = 128; st > 0; st >>= 1) {
        if (c < st) { s1[c] += s1[c + st]; s2[c] += s2[c + st]; }
        __syncthreads();
    }
    float mu = s1[0] * (1.f / CH);
    float var = s2[0] * (1.f / CH) - mu * mu;
    float r = rsqrtf(var + 1e-5f);
    out[(size_t)row * CH + c] = (v - mu) * r * g[c] + be[c];
}

__global__ __launch_bounds__(256) void k_ln(const float* __restrict__ in,
    const float* __restrict__ g, const float* __restrict__ be, float* __restrict__ out)
{
    int row = blockIdx.x;
    int c = threadIdx.x;
    float v = in[(size_t)row * CH + c];
    __shared__ float s1[256], s2[256];
    s1[c] = v; s2[c] = v * v;
    __syncthreads();
    #pragma unroll
    for (int st = 128; st > 0; st >>= 1) {
        if (c < st) { s1[c] += s1[c + st]; s2[c] += s2[c + st]; }
        __syncthreads();
    }
    float mu = s1[0] * (1.f / CH);
    float var = s2[0] * (1.f / CH) - mu * mu;
    float r = rsqrtf(var + 1e-5f);
    out[(size_t)row * CH + c] = (v - mu) * r * g[c] + be[c];
}

__global__ __launch_bounds__(256) void k_ln_out(const float* __restrict__ in,
    const float* __restrict__ g, const float* __restrict__ be, float* __restrict__ out)
{
    int row = blockIdx.x;
    int b = row / NTOK, n = row - b * NTOK;
    int c = threadIdx.x;
    float v = in[(size_t)row * CH + c];
    __shared__ float s1[256], s2[256];
    s1[c] = v; s2[c] = v * v;
    __syncthreads();
    #pragma unroll
    for (int st = 128; st > 0; st >>= 1) {
        if (c < st) { s1[c] += s1[c + st]; s2[c] += s2[c + st]; }
        __syncthreads();
    }
    float mu = s1[0] * (1.f / CH);
    float var = s2[0] * (1.f / CH) - mu * mu;
    float r = rsqrtf(var + 1e-5f);
    float val = (v - mu) * r * g[c] + be[c];
    out[((size_t)b * CH + c) * NTOK + n] = val;
}

// ---------------- GEMM: out = act(A[M,256] @ W[256,256] + bias (+resid)) ----------------
template<int ACT>
__global__ __launch_bounds__(256) void k_gemm(const float* __restrict__ A,
    const float* __restrict__ W, const float* __restrict__ bias,
    const float* __restrict__ resid, float* __restrict__ out)
{
    __shared__ float As[16][68];   // [k][m], padded
    __shared__ float Bs[16][64];   // [k][n]
    int t = threadIdx.x;
    int bm = blockIdx.x * 64;
    int bn = blockIdx.y * 64;
    int tm = (t >> 4) * 4;
    int tc = (t & 15) * 4;
    int ar = t >> 2, ac4 = (t & 3) * 4;
    int br = t >> 4, bc4 = (t & 15) * 4;
    float acc[4][4];
    #pragma unroll
    for (int i = 0; i < 4; i++)
        #pragma unroll
        for (int j = 0; j < 4; j++) acc[i][j] = 0.f;

    for (int kk = 0; kk < 256; kk += 16) {
        float4 av = *(const float4*)&A[(size_t)(bm + ar) * 256 + kk + ac4];
        As[ac4 + 0][ar] = av.x; As[ac4 + 1][ar] = av.y;
        As[ac4 + 2][ar] = av.z; As[ac4 + 3][ar] = av.w;
        float4 bv = *(const float4*)&W[(size_t)(kk + br) * 256 + bn + bc4];
        *(float4*)&Bs[br][bc4] = bv;
        __syncthreads();
        #pragma unroll
        for (int k = 0; k < 16; k++) {
            float4 a4 = *(const float4*)&As[k][tm];
            float4 b4 = *(const float4*)&Bs[k][tc];
            acc[0][0] += a4.x * b4.x; acc[0][1] += a4.x * b4.y; acc[0][2] += a4.x * b4.z; acc[0][3] += a4.x * b4.w;
            acc[1][0] += a4.y * b4.x; acc[1][1] += a4.y * b4.y; acc[1][2] += a4.y * b4.z; acc[1][3] += a4.y * b4.w;
            acc[2][0] += a4.z * b4.x; acc[2][1] += a4.z * b4.y; acc[2][2] += a4.z * b4.z; acc[2][3] += a4.z * b4.w;
            acc[3][0] += a4.w * b4.x; acc[3][1] += a4.w * b4.y; acc[3][2] += a4.w * b4.z; acc[3][3] += a4.w * b4.w;
        }
        __syncthreads();
    }
    #pragma unroll
    for (int i = 0; i < 4; i++) {
        int row = bm + tm + i;
        float4 o4;
        float* pv = (float*)&o4;
        #pragma unroll
        for (int j = 0; j < 4; j++) {
            int col = bn + tc + j;
            float vv = acc[i][j];
            if (bias)  vv += bias[col];
            if (resid) vv += resid[(size_t)row * 256 + col];
            if (ACT == 1) vv = 0.5f * vv * (1.f + erff(vv * 0.70710678118654752f));
            pv[j] = vv;
        }
        *(float4*)&out[(size_t)row * 256 + bn + tc] = o4;
    }
}

// ---------------- Attention prep: fp32 [Ns][256] head-slices -> bf16 ----------------
// qb, kb: [bh][2304][32] row-major bf16 (q pre-scaled by 1/sqrt(32))
// vt:     [bh][32][2304] bf16 (transposed)
__global__ __launch_bounds__(256) void k_prep(const float* __restrict__ Q,
    const float* __restrict__ K, const float* __restrict__ V,
    unsigned short* __restrict__ qb, unsigned short* __restrict__ kb,
    unsigned short* __restrict__ vt)
{
    int bh = blockIdx.y; int b = bh >> 3, h = bh & 7;
    int nt = blockIdx.x * 32;
    int tid = threadIdx.x;
    int n = tid >> 3, d4 = (tid & 7) * 4;
    size_t row = ((size_t)b * NTOK + nt + n) * 256 + h * 32 + d4;
    float4 qv = *(const float4*)&Q[row];
    float4 kv = *(const float4*)&K[row];
    float4 vv = *(const float4*)&V[row];
    const float sc = 0.17677669529663687f;   // 1/sqrt(32)
    ushort4 qo; qo.x = f2bf(qv.x * sc); qo.y = f2bf(qv.y * sc); qo.z = f2bf(qv.z * sc); qo.w = f2bf(qv.w * sc);
    ushort4 ko; ko.x = f2bf(kv.x); ko.y = f2bf(kv.y); ko.z = f2bf(kv.z); ko.w = f2bf(kv.w);
    size_t orow = ((size_t)bh * NTOK + nt + n) * 32 + d4;
    *(ushort4*)&qb[orow] = qo;
    *(ushort4*)&kb[orow] = ko;
    __shared__ float vs[32][33];
    vs[n][d4 + 0] = vv.x; vs[n][d4 + 1] = vv.y; vs[n][d4 + 2] = vv.z; vs[n][d4 + 3] = vv.w;
    __syncthreads();
    int d = tid >> 3, n4 = (tid & 7) * 4;
    ushort4 vo;
    vo.x = f2bf(vs[n4 + 0][d]); vo.y = f2bf(vs[n4 + 1][d]);
    vo.z = f2bf(vs[n4 + 2][d]); vo.w = f2bf(vs[n4 + 3][d]);
    *(ushort4*)&vt[((size_t)bh * 32 + d) * NTOK + nt + n4] = vo;
}

// ---------------- MFMA flash attention ----------------
// block: 16 queries (grid.x tile), 4 waves split the 2304 keys (576 each).
// Per 32-key step: S^T = mfma(K,Qt) twice; online softmax (keys lane-local);
// shuffle P into PV B-fragment; O^T += mfma(V^T, P) twice. LDS merge at end.
__global__ __launch_bounds__(256) void k_attn_mfma(
    const unsigned short* __restrict__ qb, const unsigned short* __restrict__ kb,
    const unsigned short* __restrict__ vt, float* __restrict__ O)
{
    int bh = blockIdx.y; int b = bh >> 3, h = bh & 7;
    int tid = threadIdx.x;
    int w = tid >> 6, l = tid & 63;
    int q15 = l & 15, hi = l >> 4;
    int q0 = blockIdx.x * 16;

    // Q B-fragment: B[k=d][n=q]: lane holds q=l&15, d = 8*hi + e (contig 8 bf16)
    bf16x8 qf = *(const bf16x8*)(qb + ((size_t)bh * NTOK + q0 + q15) * 32 + hi * 8);

    f32x4 cv0 = {0.f, 0.f, 0.f, 0.f};   // O^T rows d=hi*4+r,   col q
    f32x4 cv1 = {0.f, 0.f, 0.f, 0.f};   // O^T rows 16+hi*4+r
    float mrun = -1e30f, lrun = 0.f;

    const unsigned short* kbh = kb + (size_t)bh * NTOK * 32;
    const unsigned short* vbh = vt + (size_t)bh * 32 * NTOK;
    int kstart = w * (NTOK / 4);

    int sA = q15 + 16 * (2 * (hi & 1));
    int sB = sA + 16;
    bool lowhalf = hi < 2;

    for (int kt = 0; kt < NTOK / 4; kt += 32) {
        int kbase = kstart + kt;
        // K A-fragments (16 keys each): lane: key = kbase+(l&15), d = 8*hi+e
        bf16x8 kf0 = *(const bf16x8*)(kbh + (size_t)(kbase + q15) * 32 + hi * 8);
        bf16x8 kf1 = *(const bf16x8*)(kbh + (size_t)(kbase + 16 + q15) * 32 + hi * 8);
        f32x4 z = {0.f, 0.f, 0.f, 0.f};
        f32x4 s0 = __builtin_amdgcn_mfma_f32_16x16x32_bf16(kf0, qf, z, 0, 0, 0);
        f32x4 s1 = __builtin_amdgcn_mfma_f32_16x16x32_bf16(kf1, qf, z, 0, 0, 0);
        // lane holds S^T[key][q]: q = l&15, keys {4hi+r} (s0) and {16+4hi+r} (s1)

        // tile max over 32 keys of this step (per query column)
        float mx = fmaxf(fmaxf(fmaxf(s0[0], s0[1]), fmaxf(s0[2], s0[3])),
                         fmaxf(fmaxf(s1[0], s1[1]), fmaxf(s1[2], s1[3])));
        mx = fmaxf(mx, __shfl_xor(mx, 16, 64));
        mx = fmaxf(mx, __shfl_xor(mx, 32, 64));
        float mnew = fmaxf(mrun, mx);
        float corr = __expf(mrun - mnew);
        mrun = mnew;

        float p0[4], p1[4];
        float ls = 0.f;
        #pragma unroll
        for (int r = 0; r < 4; r++) {
            p0[r] = __expf(s0[r] - mnew);
            p1[r] = __expf(s1[r] - mnew);
            ls += p0[r] + p1[r];
        }
        ls += __shfl_xor(ls, 16, 64);
        ls += __shfl_xor(ls, 32, 64);
        lrun = lrun * corr + ls;

        // redistribute P into PV B-fragment: lane needs P[q][k=8*hi+e]
        float bv[8];
        #pragma unroll
        for (int r = 0; r < 4; r++) {
            float a0 = __shfl(p0[r], sA, 64);
            float a1 = __shfl(p1[r], sA, 64);
            bv[r] = lowhalf ? a0 : a1;
            float b0 = __shfl(p0[r], sB, 64);
            float b1 = __shfl(p1[r], sB, 64);
            bv[4 + r] = lowhalf ? b0 : b1;
        }
        bf16x8 pf;
        #pragma unroll
        for (int e = 0; e < 8; e++) pf[e] = (short)f2bf(bv[e]);

        // V^T A-fragments: lane: d = l&15 (+16), k = kbase + 8*hi + e (contig)
        bf16x8 v0 = *(const bf16x8*)(vbh + (size_t)q15 * NTOK + kbase + hi * 8);
        bf16x8 v1 = *(const bf16x8*)(vbh + (size_t)(q15 + 16) * NTOK + kbase + hi * 8);

        cv0 *= corr; cv1 *= corr;
        cv0 = __builtin_amdgcn_mfma_f32_16x16x32_bf16(v0, pf, cv0, 0, 0, 0);
        cv1 = __builtin_amdgcn_mfma_f32_16x16x32_bf16(v1, pf, cv1, 0, 0, 0);
    }

    // merge the 4 key-split partials via LDS
    __shared__ float lm[4][16], ll[4][16];
    __shared__ float lo[4][16][32];
    if (hi == 0) { lm[w][q15] = mrun; ll[w][q15] = lrun; }
    #pragma unroll
    for (int r = 0; r < 4; r++) {
        lo[w][q15][hi * 4 + r]      = cv0[r];
        lo[w][q15][16 + hi * 4 + r] = cv1[r];
    }
    __syncthreads();

    int q = tid >> 4;            // 0..15
    int d0 = (tid & 15) * 2;     // 0..30
    float M = fmaxf(fmaxf(lm[0][q], lm[1][q]), fmaxf(lm[2][q], lm[3][q]));
    float wgt[4]; float L = 0.f;
    #pragma unroll
    for (int s = 0; s < 4; s++) { wgt[s] = __expf(lm[s][q] - M); L += ll[s][q] * wgt[s]; }
    float invL = 1.f / L;
    float2 o2;
    o2.x = (lo[0][q][d0]     * wgt[0] + lo[1][q][d0]     * wgt[1]
          + lo[2][q][d0]     * wgt[2] + lo[3][q][d0]     * wgt[3]) * invL;
    o2.y = (lo[0][q][d0 + 1] * wgt[0] + lo[1][q][d0 + 1] * wgt[1]
          + lo[2][q][d0 + 1] * wgt[2] + lo[3][q][d0 + 1] * wgt[3]) * invL;
    *(float2*)&O[((size_t)(b * NTOK + q0 + q)) * 256 + h * 32 + d0] = o2;
}

// ---------------- GAT pieces ----------------

__global__ __launch_bounds__(256) void k_attvec(const float* __restrict__ h,
    const float* __restrict__ wsrc, const float* __restrict__ wdst,
    float* __restrict__ a_src, float* __restrict__ a_dst)
{
    int node = blockIdx.x;
    int c = threadIdx.x;
    float hv = h[(size_t)node * CH + c];
    __shared__ float s1[256], s2[256];
    s1[c] = hv * wsrc[c]; s2[c] = hv * wdst[c];
    __syncthreads();
    #pragma unroll
    for (int st = 128; st > 0; st >>= 1) {
        if (c < st) { s1[c] += s1[c + st]; s2[c] += s2[c + st]; }
        __syncthreads();
    }
    if (c == 0) { a_src[node] = s1[0]; a_dst[node] = s2[0]; }
}

__global__ void k_fill_edges(const int* __restrict__ ei, int Eed,
    int* __restrict__ deg, int* __restrict__ csr)
{
    int e = blockIdx.x * 256 + threadIdx.x;
    if (e >= Eed) return;
    int src = ei[e];
    int dst = ei[Eed + e];
    int pos = atomicAdd(&deg[dst], 1);
    if (pos < 16) csr[dst * 16 + pos] = src;
}

__global__ __launch_bounds__(256) void k_gat_agg(const int* __restrict__ deg,
    const int* __restrict__ csr, const float* __restrict__ a_src,
    const float* __restrict__ a_dst, const float* __restrict__ h,
    const float* __restrict__ gbias, float* __restrict__ nf)
{
    int dst = blockIdx.x;
    int t = threadIdx.x;
    __shared__ float logit[16];
    __shared__ float alpha[16];
    __shared__ int srcs[16];
    int cnt = deg[dst]; if (cnt > 16) cnt = 16;
    if (t < cnt) {
        int s = csr[dst * 16 + t];
        srcs[t] = s;
        float lg = a_src[s] + a_dst[dst];
        logit[t] = lg > 0.f ? lg : 0.2f * lg;
    }
    __syncthreads();
    if (t == 0) {
        float mx = -1e30f;
        for (int i = 0; i < cnt; i++) mx = fmaxf(mx, logit[i]);
        float dn = 0.f;
        for (int i = 0; i < cnt; i++) { float ex = __expf(logit[i] - mx); alpha[i] = ex; dn += ex; }
        float inv = 1.f / (dn + 1e-16f);
        for (int i = 0; i < cnt; i++) alpha[i] *= inv;
    }
    __syncthreads();
    float accv = 0.f;
    for (int i = 0; i < cnt; i++) accv += alpha[i] * h[(size_t)srcs[i] * CH + t];
    float val = accv + gbias[t];
    val = val > 0.f ? val : expm1f(val);
    nf[(size_t)dst * CH + t] += val;
}

// ---------------- orchestration ----------------
extern "C" void kernel_launch(void* const* d_in, const int* in_sizes, int n_in,
                              void* d_out, int out_size, void* d_ws, size_t ws_size,
                              hipStream_t stream)
{
    const float* x_cnn   = (const float*)d_in[0];
    const int*   edge    = (const int*)d_in[1];
    const float* norm1_g = (const float*)d_in[2];
    const float* norm1_b = (const float*)d_in[3];
    const float* proj_w  = (const float*)d_in[4];
    const float* proj_b  = (const float*)d_in[5];
    const float* wq      = (const float*)d_in[6];
    const float* bq      = (const float*)d_in[7];
    const float* wk      = (const float*)d_in[8];
    const float* bk      = (const float*)d_in[9];
    const float* wv      = (const float*)d_in[10];
    const float* bv      = (const float*)d_in[11];
    const float* wo      = (const float*)d_in[12];
    const float* bo      = (const float*)d_in[13];
    const float* norm2_g = (const float*)d_in[14];
    const float* norm2_b = (const float*)d_in[15];
    const float* gpl_w   = (const float*)d_in[16];
    const float* gpl_b   = (const float*)d_in[17];
    const float* gat_w   = (const float*)d_in[18];
    const float* att_src = (const float*)d_in[19];
    const float* att_dst = (const float*)d_in[20];
    const float* gat_bias= (const float*)d_in[21];
    const float* norm3_g = (const float*)d_in[22];
    const float* norm3_b = (const float*)d_in[23];
    const float* mlp_w1  = (const float*)d_in[24];
    const float* mlp_b1  = (const float*)d_in[25];
    const float* mlp_w2  = (const float*)d_in[26];
    const float* mlp_b2  = (const float*)d_in[27];
    const float* fn_g    = (const float*)d_in[28];
    const float* fn_b    = (const float*)d_in[29];

    int Eed = in_sizes[1] / 2;
    float* out = (float*)d_out;

    const size_t NB = (size_t)NS * CH;   // 1,179,648 floats per buffer
    float* ws   = (float*)d_ws;
    float* bufA = ws + 0 * NB;
    float* bufB = ws + 1 * NB;
    float* bufC = ws + 2 * NB;
    float* bufD = ws + 3 * NB;
    float* bufE = ws + 4 * NB;
    float* a_src = ws + 5 * NB;
    float* a_dst = a_src + NS;
    int*   deg   = (int*)(a_dst + NS);
    int*   csr   = deg + NS;             // NS*16 ints
    unsigned short* qb = (unsigned short*)(csr + (size_t)NS * 16);
    unsigned short* kb = qb + NB;        // NB ushorts each (16*2304*32)
    unsigned short* vt = kb + NB;
    // total ws use: ~24 MB + 7.1 MB bf16 ≈ 31 MB

    dim3 g72(72, 4);

    // 1. tokenize + LN1 -> bufA
    k_ln_tok<<<NS, 256, 0, stream>>>(x_cnn, norm1_g, norm1_b, bufA);
    // 2. xv = bufA @ proj + proj_b -> bufB
    k_gemm<0><<<g72, 256, 0, stream>>>(bufA, proj_w, proj_b, nullptr, bufB);
    // 3. q,k,v
    k_gemm<0><<<g72, 256, 0, stream>>>(bufB, wq, bq, nullptr, bufC);
    k_gemm<0><<<g72, 256, 0, stream>>>(bufB, wk, bk, nullptr, bufD);
    k_gemm<0><<<g72, 256, 0, stream>>>(bufB, wv, bv, nullptr, bufE);
    // 4. prep bf16 Q/K/V^T
    k_prep<<<dim3(72, 16), 256, 0, stream>>>(bufC, bufD, bufE, qb, kb, vt);
    // 5. MFMA flash attention -> bufA
    k_attn_mfma<<<dim3(144, 16), 256, 0, stream>>>(qb, kb, vt, bufA);
    // 6. nf = bufB + bufA @ wo + bo  (in-place into bufB)
    k_gemm<0><<<g72, 256, 0, stream>>>(bufA, wo, bo, bufB, bufB);
    // 7. ln2 -> bufC
    k_ln<<<NS, 256, 0, stream>>>(bufB, norm2_g, norm2_b, bufC);
    // 8. xg = bufC @ gpl_w + gpl_b -> bufD
    k_gemm<0><<<g72, 256, 0, stream>>>(bufC, gpl_w, gpl_b, nullptr, bufD);
    // 9. h = bufD @ gat_w -> bufE
    k_gemm<0><<<g72, 256, 0, stream>>>(bufD, gat_w, nullptr, nullptr, bufE);
    // 10. a_src/a_dst
    k_attvec<<<NS, 256, 0, stream>>>(bufE, att_src, att_dst, a_src, a_dst);
    // 11. CSR build
    hipMemsetAsync(deg, 0, NS * sizeof(int), stream);
    k_fill_edges<<<(Eed + 255) / 256, 256, 0, stream>>>(edge, Eed, deg, csr);
    // 12. GAT aggregate + elu + residual (bufB updated in place)
    k_gat_agg<<<NS, 256, 0, stream>>>(deg, csr, a_src, a_dst, bufE, gat_bias, bufB);
    // 13. ln3 -> bufC
    k_ln<<<NS, 256, 0, stream>>>(bufB, norm3_g, norm3_b, bufC);
    // 14. mlp1 = gelu(bufC @ mlp_w1 + b1) -> bufD
    k_gemm<1><<<g72, 256, 0, stream>>>(bufC, mlp_w1, mlp_b1, nullptr, bufD);
    // 15. y_pre = bufC + bufD @ mlp_w2 + b2 -> bufA
    k_gemm<0><<<g72, 256, 0, stream>>>(bufD, mlp_w2, mlp_b2, bufC, bufA);
    // 16. final LN + transpose -> out
    k_ln_out<<<NS, 256, 0, stream>>>(bufA, fn_g, fn_b, out);
}

// Round 4
// 223.725 us; speedup vs baseline: 5.3492x; 1.3081x over previous
//
#include <hip/hip_runtime.h>
#include <math.h>

// Problem constants (B=2, H=W=48, C=E=256, NH=8, GH=1)
#define NTOK 2304              // H*W
#define NS   4608              // B*NTOK
#define CH   256               // C == E == E*GH

using bf16x8 = __attribute__((ext_vector_type(8))) short;
using f32x4  = __attribute__((ext_vector_type(4))) float;

__device__ __forceinline__ unsigned short f2bf(float x) {
    unsigned int u = __float_as_uint(x);
    u = (u + 0x7fffu + ((u >> 16) & 1u)) >> 16;   // RNE
    return (unsigned short)u;
}

// ---------------- block LN reduce: wave shfl + 1 barrier ----------------
__device__ __forceinline__ void red2(float& a, float& b, float* s1, float* s2) {
    #pragma unroll
    for (int off = 32; off; off >>= 1) {
        a += __shfl_xor(a, off, 64);
        b += __shfl_xor(b, off, 64);
    }
    int t = threadIdx.x;
    if ((t & 63) == 0) { s1[t >> 6] = a; s2[t >> 6] = b; }
    __syncthreads();
    a = s1[0] + s1[1] + s1[2] + s1[3];
    b = s2[0] + s2[1] + s2[2] + s2[3];
}

// LN over channel dim while transposing [B,C,N] -> [Ns, C]
__global__ __launch_bounds__(256) void k_ln_tok(const float* __restrict__ x,
    const float* __restrict__ g, const float* __restrict__ be, float* __restrict__ out)
{
    int row = blockIdx.x;              // b*NTOK + n
    int b = row / NTOK, n = row - b * NTOK;
    int c = threadIdx.x;
    float v = x[((size_t)b * CH + c) * NTOK + n];
    __shared__ float s1[4], s2[4];
    float a = v, q = v * v;
    red2(a, q, s1, s2);
    float mu = a * (1.f / CH);
    float var = q * (1.f / CH) - mu * mu;
    float r = rsqrtf(var + 1e-5f);
    out[(size_t)row * CH + c] = (v - mu) * r * g[c] + be[c];
}

__global__ __launch_bounds__(256) void k_ln(const float* __restrict__ in,
    const float* __restrict__ g, const float* __restrict__ be, float* __restrict__ out)
{
    int row = blockIdx.x;
    int c = threadIdx.x;
    float v = in[(size_t)row * CH + c];
    __shared__ float s1[4], s2[4];
    float a = v, q = v * v;
    red2(a, q, s1, s2);
    float mu = a * (1.f / CH);
    float var = q * (1.f / CH) - mu * mu;
    float r = rsqrtf(var + 1e-5f);
    out[(size_t)row * CH + c] = (v - mu) * r * g[c] + be[c];
}

// final LN + transpose to [B, E, H*W]
__global__ __launch_bounds__(256) void k_ln_out(const float* __restrict__ in,
    const float* __restrict__ g, const float* __restrict__ be, float* __restrict__ out)
{
    int row = blockIdx.x;
    int b = row / NTOK, n = row - b * NTOK;
    int c = threadIdx.x;
    float v = in[(size_t)row * CH + c];
    __shared__ float s1[4], s2[4];
    float a = v, q = v * v;
    red2(a, q, s1, s2);
    float mu = a * (1.f / CH);
    float var = q * (1.f / CH) - mu * mu;
    float r = rsqrtf(var + 1e-5f);
    float val = (v - mu) * r * g[c] + be[c];
    out[((size_t)b * CH + c) * NTOK + n] = val;
}

// ---------------- weight prep: fp32 W[k][n] -> bf16 Wt[n][k], 9 matrices ----------------
__global__ __launch_bounds__(256) void k_wprep(
    const float* __restrict__ w0, const float* __restrict__ w1,
    const float* __restrict__ w2, const float* __restrict__ w3,
    const float* __restrict__ w4, const float* __restrict__ w5,
    const float* __restrict__ w6, const float* __restrict__ w7,
    const float* __restrict__ w8, unsigned short* __restrict__ wt)
{
    const float* W;
    switch (blockIdx.z) {
        case 0: W = w0; break; case 1: W = w1; break; case 2: W = w2; break;
        case 3: W = w3; break; case 4: W = w4; break; case 5: W = w5; break;
        case 6: W = w6; break; case 7: W = w7; break; default: W = w8; break;
    }
    unsigned short* out = wt + (size_t)blockIdx.z * 65536;
    __shared__ float fs[32][33];
    int tid = threadIdx.x;
    int bk = blockIdx.x * 32, bn = blockIdx.y * 32;
    int k = tid >> 3, n4 = (tid & 7) * 4;
    float4 v = *(const float4*)&W[(size_t)(bk + k) * 256 + bn + n4];
    fs[k][n4] = v.x; fs[k][n4 + 1] = v.y; fs[k][n4 + 2] = v.z; fs[k][n4 + 3] = v.w;
    __syncthreads();
    int n = tid >> 3, k4 = (tid & 7) * 4;
    ushort4 o;
    o.x = f2bf(fs[k4 + 0][n]); o.y = f2bf(fs[k4 + 1][n]);
    o.z = f2bf(fs[k4 + 2][n]); o.w = f2bf(fs[k4 + 3][n]);
    *(ushort4*)&out[(size_t)(bn + n) * 256 + bk + k4] = o;
}

// ---------------- MFMA GEMM: out = epi(A[M,256] @ W + bias (+resid)) ----------------
// A fp32 row-major; Wt bf16 [n][k]. Tile 64(M)x32(N), 4 waves each 16x32.
// EPI: 0 = fp32 [M][256] (+resid, ACT1 = exact gelu)
//      1 = bf16 [bh][tok][32] (value scaled by `scale`)   (Q/K layout)
//      2 = bf16 [bh][32][tok]                             (V^T layout)
template<int EPI, int ACT>
__global__ __launch_bounds__(256) void k_gemm_mfma(const float* __restrict__ A,
    const unsigned short* __restrict__ Wt, const float* __restrict__ bias,
    const float* __restrict__ resid, void* __restrict__ outp, float scale)
{
    __shared__ unsigned short As[64][40];   // 32 k padded to 40 (2-way conflict = free)
    int tid = threadIdx.x;
    int w = tid >> 6, l = tid & 63;
    int l15 = l & 15, hi = l >> 4;
    int bm = blockIdx.x * 64, bn = blockIdx.y * 32;

    f32x4 acc0 = {0.f, 0.f, 0.f, 0.f};
    f32x4 acc1 = {0.f, 0.f, 0.f, 0.f};
    int r0 = tid >> 3, kq = (tid & 7) * 4;

    for (int kk = 0; kk < 256; kk += 32) {
        float4 a0 = *(const float4*)&A[(size_t)(bm + r0) * 256 + kk + kq];
        float4 a1 = *(const float4*)&A[(size_t)(bm + r0 + 32) * 256 + kk + kq];
        ushort4 u0, u1;
        u0.x = f2bf(a0.x); u0.y = f2bf(a0.y); u0.z = f2bf(a0.z); u0.w = f2bf(a0.w);
        u1.x = f2bf(a1.x); u1.y = f2bf(a1.y); u1.z = f2bf(a1.z); u1.w = f2bf(a1.w);
        *(ushort4*)&As[r0][kq] = u0;
        *(ushort4*)&As[r0 + 32][kq] = u1;
        __syncthreads();
        // A-frag: row = w*16 + l15, k = hi*8+e (contig)
        bf16x8 af = *(const bf16x8*)&As[w * 16 + l15][hi * 8];
        // B-frags direct from global (L2-resident): col = l15 (+16), k contig
        bf16x8 b0 = *(const bf16x8*)&Wt[(size_t)(bn + l15) * 256 + kk + hi * 8];
        bf16x8 b1 = *(const bf16x8*)&Wt[(size_t)(bn + 16 + l15) * 256 + kk + hi * 8];
        acc0 = __builtin_amdgcn_mfma_f32_16x16x32_bf16(af, b0, acc0, 0, 0, 0);
        acc1 = __builtin_amdgcn_mfma_f32_16x16x32_bf16(af, b1, acc1, 0, 0, 0);
        __syncthreads();
    }

    float* outf = (float*)outp;
    unsigned short* outb = (unsigned short*)outp;
    #pragma unroll
    for (int j = 0; j < 2; j++) {
        #pragma unroll
        for (int r = 0; r < 4; r++) {
            float vv = (j == 0) ? acc0[r] : acc1[r];
            int gcol = bn + j * 16 + l15;
            int grow = bm + w * 16 + hi * 4 + r;   // C: col=lane&15, row=4*(l>>4)+reg
            if (bias) vv += bias[gcol];
            if (EPI == 0) {
                if (resid) vv += resid[(size_t)grow * 256 + gcol];
                if (ACT == 1) vv = 0.5f * vv * (1.f + erff(vv * 0.70710678118654752f));
                outf[(size_t)grow * 256 + gcol] = vv;
            } else {
                int b = grow >= NTOK;
                int tok = grow - b * NTOK;
                int h = gcol >> 5, d = gcol & 31;
                if (EPI == 1)
                    outb[(((size_t)(b * 8 + h)) * NTOK + tok) * 32 + d] = f2bf(vv * scale);
                else
                    outb[((size_t)(b * 8 + h) * 32 + d) * NTOK + tok] = f2bf(vv);
            }
        }
    }
}

// ---------------- MFMA flash attention (unchanged from round 3) ----------------
__global__ __launch_bounds__(256) void k_attn_mfma(
    const unsigned short* __restrict__ qb, const unsigned short* __restrict__ kb,
    const unsigned short* __restrict__ vt, float* __restrict__ O)
{
    int bh = blockIdx.y; int b = bh >> 3, h = bh & 7;
    int tid = threadIdx.x;
    int w = tid >> 6, l = tid & 63;
    int q15 = l & 15, hi = l >> 4;
    int q0 = blockIdx.x * 16;

    bf16x8 qf = *(const bf16x8*)(qb + ((size_t)bh * NTOK + q0 + q15) * 32 + hi * 8);

    f32x4 cv0 = {0.f, 0.f, 0.f, 0.f};
    f32x4 cv1 = {0.f, 0.f, 0.f, 0.f};
    float mrun = -1e30f, lrun = 0.f;

    const unsigned short* kbh = kb + (size_t)bh * NTOK * 32;
    const unsigned short* vbh = vt + (size_t)bh * 32 * NTOK;
    int kstart = w * (NTOK / 4);

    int sA = q15 + 16 * (2 * (hi & 1));
    int sB = sA + 16;
    bool lowhalf = hi < 2;

    for (int kt = 0; kt < NTOK / 4; kt += 32) {
        int kbase = kstart + kt;
        bf16x8 kf0 = *(const bf16x8*)(kbh + (size_t)(kbase + q15) * 32 + hi * 8);
        bf16x8 kf1 = *(const bf16x8*)(kbh + (size_t)(kbase + 16 + q15) * 32 + hi * 8);
        f32x4 z = {0.f, 0.f, 0.f, 0.f};
        f32x4 s0 = __builtin_amdgcn_mfma_f32_16x16x32_bf16(kf0, qf, z, 0, 0, 0);
        f32x4 s1 = __builtin_amdgcn_mfma_f32_16x16x32_bf16(kf1, qf, z, 0, 0, 0);

        float mx = fmaxf(fmaxf(fmaxf(s0[0], s0[1]), fmaxf(s0[2], s0[3])),
                         fmaxf(fmaxf(s1[0], s1[1]), fmaxf(s1[2], s1[3])));
        mx = fmaxf(mx, __shfl_xor(mx, 16, 64));
        mx = fmaxf(mx, __shfl_xor(mx, 32, 64));
        float mnew = fmaxf(mrun, mx);
        float corr = __expf(mrun - mnew);
        mrun = mnew;

        float p0[4], p1[4];
        float ls = 0.f;
        #pragma unroll
        for (int r = 0; r < 4; r++) {
            p0[r] = __expf(s0[r] - mnew);
            p1[r] = __expf(s1[r] - mnew);
            ls += p0[r] + p1[r];
        }
        ls += __shfl_xor(ls, 16, 64);
        ls += __shfl_xor(ls, 32, 64);
        lrun = lrun * corr + ls;

        float bv[8];
        #pragma unroll
        for (int r = 0; r < 4; r++) {
            float a0 = __shfl(p0[r], sA, 64);
            float a1 = __shfl(p1[r], sA, 64);
            bv[r] = lowhalf ? a0 : a1;
            float b0 = __shfl(p0[r], sB, 64);
            float b1 = __shfl(p1[r], sB, 64);
            bv[4 + r] = lowhalf ? b0 : b1;
        }
        bf16x8 pf;
        #pragma unroll
        for (int e = 0; e < 8; e++) pf[e] = (short)f2bf(bv[e]);

        bf16x8 v0 = *(const bf16x8*)(vbh + (size_t)q15 * NTOK + kbase + hi * 8);
        bf16x8 v1 = *(const bf16x8*)(vbh + (size_t)(q15 + 16) * NTOK + kbase + hi * 8);

        cv0 *= corr; cv1 *= corr;
        cv0 = __builtin_amdgcn_mfma_f32_16x16x32_bf16(v0, pf, cv0, 0, 0, 0);
        cv1 = __builtin_amdgcn_mfma_f32_16x16x32_bf16(v1, pf, cv1, 0, 0, 0);
    }

    __shared__ float lm[4][16], ll[4][16];
    __shared__ float lo[4][16][32];
    if (hi == 0) { lm[w][q15] = mrun; ll[w][q15] = lrun; }
    #pragma unroll
    for (int r = 0; r < 4; r++) {
        lo[w][q15][hi * 4 + r]      = cv0[r];
        lo[w][q15][16 + hi * 4 + r] = cv1[r];
    }
    __syncthreads();

    int q = tid >> 4;
    int d0 = (tid & 15) * 2;
    float M = fmaxf(fmaxf(lm[0][q], lm[1][q]), fmaxf(lm[2][q], lm[3][q]));
    float wgt[4]; float L = 0.f;
    #pragma unroll
    for (int s = 0; s < 4; s++) { wgt[s] = __expf(lm[s][q] - M); L += ll[s][q] * wgt[s]; }
    float invL = 1.f / L;
    float2 o2;
    o2.x = (lo[0][q][d0]     * wgt[0] + lo[1][q][d0]     * wgt[1]
          + lo[2][q][d0]     * wgt[2] + lo[3][q][d0]     * wgt[3]) * invL;
    o2.y = (lo[0][q][d0 + 1] * wgt[0] + lo[1][q][d0 + 1] * wgt[1]
          + lo[2][q][d0 + 1] * wgt[2] + lo[3][q][d0 + 1] * wgt[3]) * invL;
    *(float2*)&O[((size_t)(b * NTOK + q0 + q)) * 256 + h * 32 + d0] = o2;
}

// ---------------- GAT pieces ----------------

__global__ __launch_bounds__(256) void k_attvec(const float* __restrict__ h,
    const float* __restrict__ wsrc, const float* __restrict__ wdst,
    float* __restrict__ a_src, float* __restrict__ a_dst)
{
    int node = blockIdx.x;
    int c = threadIdx.x;
    float hv = h[(size_t)node * CH + c];
    __shared__ float s1[4], s2[4];
    float a = hv * wsrc[c], q = hv * wdst[c];
    red2(a, q, s1, s2);
    if (c == 0) { a_src[node] = a; a_dst[node] = q; }
}

__global__ void k_fill_edges(const int* __restrict__ ei, int Eed,
    int* __restrict__ deg, int* __restrict__ csr)
{
    int e = blockIdx.x * 256 + threadIdx.x;
    if (e >= Eed) return;
    int src = ei[e];
    int dst = ei[Eed + e];
    int pos = atomicAdd(&deg[dst], 1);
    if (pos < 16) csr[dst * 16 + pos] = src;
}

__global__ __launch_bounds__(256) void k_gat_agg(const int* __restrict__ deg,
    const int* __restrict__ csr, const float* __restrict__ a_src,
    const float* __restrict__ a_dst, const float* __restrict__ h,
    const float* __restrict__ gbias, float* __restrict__ nf)
{
    int dst = blockIdx.x;
    int t = threadIdx.x;
    __shared__ float logit[16];
    __shared__ float alpha[16];
    __shared__ int srcs[16];
    int cnt = deg[dst]; if (cnt > 16) cnt = 16;
    if (t < cnt) {
        int s = csr[dst * 16 + t];
        srcs[t] = s;
        float lg = a_src[s] + a_dst[dst];
        logit[t] = lg > 0.f ? lg : 0.2f * lg;
    }
    __syncthreads();
    if (t == 0) {
        float mx = -1e30f;
        for (int i = 0; i < cnt; i++) mx = fmaxf(mx, logit[i]);
        float dn = 0.f;
        for (int i = 0; i < cnt; i++) { float ex = __expf(logit[i] - mx); alpha[i] = ex; dn += ex; }
        float inv = 1.f / (dn + 1e-16f);
        for (int i = 0; i < cnt; i++) alpha[i] *= inv;
    }
    __syncthreads();
    float accv = 0.f;
    for (int i = 0; i < cnt; i++) accv += alpha[i] * h[(size_t)srcs[i] * CH + t];
    float val = accv + gbias[t];
    val = val > 0.f ? val : expm1f(val);
    nf[(size_t)dst * CH + t] += val;
}

// ---------------- orchestration ----------------
extern "C" void kernel_launch(void* const* d_in, const int* in_sizes, int n_in,
                              void* d_out, int out_size, void* d_ws, size_t ws_size,
                              hipStream_t stream)
{
    const float* x_cnn   = (const float*)d_in[0];
    const int*   edge    = (const int*)d_in[1];
    const float* norm1_g = (const float*)d_in[2];
    const float* norm1_b = (const float*)d_in[3];
    const float* proj_w  = (const float*)d_in[4];
    const float* proj_b  = (const float*)d_in[5];
    const float* wq      = (const float*)d_in[6];
    const float* bq      = (const float*)d_in[7];
    const float* wk      = (const float*)d_in[8];
    const float* bk      = (const float*)d_in[9];
    const float* wv      = (const float*)d_in[10];
    const float* bv      = (const float*)d_in[11];
    const float* wo      = (const float*)d_in[12];
    const float* bo      = (const float*)d_in[13];
    const float* norm2_g = (const float*)d_in[14];
    const float* norm2_b = (const float*)d_in[15];
    const float* gpl_w   = (const float*)d_in[16];
    const float* gpl_b   = (const float*)d_in[17];
    const float* gat_w   = (const float*)d_in[18];
    const float* att_src = (const float*)d_in[19];
    const float* att_dst = (const float*)d_in[20];
    const float* gat_bias= (const float*)d_in[21];
    const float* norm3_g = (const float*)d_in[22];
    const float* norm3_b = (const float*)d_in[23];
    const float* mlp_w1  = (const float*)d_in[24];
    const float* mlp_b1  = (const float*)d_in[25];
    const float* mlp_w2  = (const float*)d_in[26];
    const float* mlp_b2  = (const float*)d_in[27];
    const float* fn_g    = (const float*)d_in[28];
    const float* fn_b    = (const float*)d_in[29];

    int Eed = in_sizes[1] / 2;
    float* out = (float*)d_out;

    const size_t NB = (size_t)NS * CH;   // 1,179,648
    float* ws   = (float*)d_ws;
    float* bufA = ws + 0 * NB;
    float* bufB = ws + 1 * NB;
    float* bufC = ws + 2 * NB;
    float* bufD = ws + 3 * NB;
    float* bufE = ws + 4 * NB;
    float* a_src = ws + 5 * NB;
    float* a_dst = a_src + NS;
    int*   deg   = (int*)(a_dst + NS);
    int*   csr   = deg + NS;             // NS*16 ints
    unsigned short* qb = (unsigned short*)(csr + (size_t)NS * 16);
    unsigned short* kb = qb + NB;
    unsigned short* vt = kb + NB;
    unsigned short* wt = vt + NB;        // 9 * 65536 bf16 transposed weights
    // total ws ≈ 33 MB

    const float qscale = 0.17677669529663687f;   // 1/sqrt(32)
    dim3 gg(72, 8);       // 64x32 tiles over 4608x256
    dim3 gw(8, 8, 9);

    // 0. transpose+convert all weights to bf16 [n][k]
    k_wprep<<<gw, 256, 0, stream>>>(proj_w, wq, wk, wv, wo, gpl_w, gat_w,
                                    mlp_w1, mlp_w2, wt);
    // 1. tokenize + LN1 -> bufA
    k_ln_tok<<<NS, 256, 0, stream>>>(x_cnn, norm1_g, norm1_b, bufA);
    // 2. xv = bufA @ proj + proj_b -> bufB (fp32)
    k_gemm_mfma<0,0><<<gg, 256, 0, stream>>>(bufA, wt + 0 * 65536, proj_b, nullptr, bufB, 1.f);
    // 3. q,k (bf16 attn layout, q scaled), v (bf16 transposed)
    k_gemm_mfma<1,0><<<gg, 256, 0, stream>>>(bufB, wt + 1 * 65536, bq, nullptr, qb, qscale);
    k_gemm_mfma<1,0><<<gg, 256, 0, stream>>>(bufB, wt + 2 * 65536, bk, nullptr, kb, 1.f);
    k_gemm_mfma<2,0><<<gg, 256, 0, stream>>>(bufB, wt + 3 * 65536, bv, nullptr, vt, 1.f);
    // 4. MFMA flash attention -> bufA
    k_attn_mfma<<<dim3(144, 16), 256, 0, stream>>>(qb, kb, vt, bufA);
    // 5. nf = bufB + bufA @ wo + bo  (in-place into bufB)
    k_gemm_mfma<0,0><<<gg, 256, 0, stream>>>(bufA, wt + 4 * 65536, bo, bufB, bufB, 1.f);
    // 6. ln2 -> bufC
    k_ln<<<NS, 256, 0, stream>>>(bufB, norm2_g, norm2_b, bufC);
    // 7. xg = bufC @ gpl_w + gpl_b -> bufD
    k_gemm_mfma<0,0><<<gg, 256, 0, stream>>>(bufC, wt + 5 * 65536, gpl_b, nullptr, bufD, 1.f);
    // 8. h = bufD @ gat_w -> bufE
    k_gemm_mfma<0,0><<<gg, 256, 0, stream>>>(bufD, wt + 6 * 65536, nullptr, nullptr, bufE, 1.f);
    // 9. a_src/a_dst
    k_attvec<<<NS, 256, 0, stream>>>(bufE, att_src, att_dst, a_src, a_dst);
    // 10. CSR build
    hipMemsetAsync(deg, 0, NS * sizeof(int), stream);
    k_fill_edges<<<(Eed + 255) / 256, 256, 0, stream>>>(edge, Eed, deg, csr);
    // 11. GAT aggregate + elu + residual (bufB updated in place)
    k_gat_agg<<<NS, 256, 0, stream>>>(deg, csr, a_src, a_dst, bufE, gat_bias, bufB);
    // 12. ln3 -> bufC
    k_ln<<<NS, 256, 0, stream>>>(bufB, norm3_g, norm3_b, bufC);
    // 13. mlp1 = gelu(bufC @ mlp_w1 + b1) -> bufD
    k_gemm_mfma<0,1><<<gg, 256, 0, stream>>>(bufC, wt + 7 * 65536, mlp_b1, nullptr, bufD, 1.f);
    // 14. y_pre = bufC + bufD @ mlp_w2 + b2 -> bufA
    k_gemm_mfma<0,0><<<gg, 256, 0, stream>>>(bufD, wt + 8 * 65536, mlp_b2, bufC, bufA, 1.f);
    // 15. final LN + transpose -> out
    k_ln_out<<<NS, 256, 0, stream>>>(bufA, fn_g, fn_b, out);
}

// Round 6
// 222.413 us; speedup vs baseline: 5.3808x; 1.0059x over previous
//
#include <hip/hip_runtime.h>
#include <math.h>

// Problem constants (B=2, H=W=48, C=E=256, NH=8, GH=1)
#define NTOK 2304              // H*W
#define NS   4608              // B*NTOK
#define CH   256               // C == E == E*GH

using bf16x8 = __attribute__((ext_vector_type(8))) short;
using f32x4  = __attribute__((ext_vector_type(4))) float;

#define EXP2F(x) __builtin_amdgcn_exp2f(x)

__device__ __forceinline__ unsigned short f2bf(float x) {
    unsigned int u = __float_as_uint(x);
    u = (u + 0x7fffu + ((u >> 16) & 1u)) >> 16;   // RNE
    return (unsigned short)u;
}

// ---------------- block LN reduce: wave shfl + 1 barrier ----------------
__device__ __forceinline__ void red2(float& a, float& b, float* s1, float* s2) {
    #pragma unroll
    for (int off = 32; off; off >>= 1) {
        a += __shfl_xor(a, off, 64);
        b += __shfl_xor(b, off, 64);
    }
    int t = threadIdx.x;
    if ((t & 63) == 0) { s1[t >> 6] = a; s2[t >> 6] = b; }
    __syncthreads();
    a = s1[0] + s1[1] + s1[2] + s1[3];
    b = s2[0] + s2[1] + s2[2] + s2[3];
}

// LN over channel dim while transposing [B,C,N] -> [Ns, C]
__global__ __launch_bounds__(256) void k_ln_tok(const float* __restrict__ x,
    const float* __restrict__ g, const float* __restrict__ be, float* __restrict__ out)
{
    int row = blockIdx.x;              // b*NTOK + n
    int b = row / NTOK, n = row - b * NTOK;
    int c = threadIdx.x;
    float v = x[((size_t)b * CH + c) * NTOK + n];
    __shared__ float s1[4], s2[4];
    float a = v, q = v * v;
    red2(a, q, s1, s2);
    float mu = a * (1.f / CH);
    float var = q * (1.f / CH) - mu * mu;
    float r = rsqrtf(var + 1e-5f);
    out[(size_t)row * CH + c] = (v - mu) * r * g[c] + be[c];
}

__global__ __launch_bounds__(256) void k_ln(const float* __restrict__ in,
    const float* __restrict__ g, const float* __restrict__ be, float* __restrict__ out)
{
    int row = blockIdx.x;
    int c = threadIdx.x;
    float v = in[(size_t)row * CH + c];
    __shared__ float s1[4], s2[4];
    float a = v, q = v * v;
    red2(a, q, s1, s2);
    float mu = a * (1.f / CH);
    float var = q * (1.f / CH) - mu * mu;
    float r = rsqrtf(var + 1e-5f);
    out[(size_t)row * CH + c] = (v - mu) * r * g[c] + be[c];
}

// final LN + transpose to [B, E, H*W]
__global__ __launch_bounds__(256) void k_ln_out(const float* __restrict__ in,
    const float* __restrict__ g, const float* __restrict__ be, float* __restrict__ out)
{
    int row = blockIdx.x;
    int b = row / NTOK, n = row - b * NTOK;
    int c = threadIdx.x;
    float v = in[(size_t)row * CH + c];
    __shared__ float s1[4], s2[4];
    float a = v, q = v * v;
    red2(a, q, s1, s2);
    float mu = a * (1.f / CH);
    float var = q * (1.f / CH) - mu * mu;
    float r = rsqrtf(var + 1e-5f);
    float val = (v - mu) * r * g[c] + be[c];
    out[((size_t)b * CH + c) * NTOK + n] = val;
}

// ---------------- weight prep: fp32 W[k][n] -> bf16 Wt[n][k], 9 matrices ----------------
__global__ __launch_bounds__(256) void k_wprep(
    const float* __restrict__ w0, const float* __restrict__ w1,
    const float* __restrict__ w2, const float* __restrict__ w3,
    const float* __restrict__ w4, const float* __restrict__ w5,
    const float* __restrict__ w6, const float* __restrict__ w7,
    const float* __restrict__ w8, unsigned short* __restrict__ wt)
{
    const float* W;
    switch (blockIdx.z) {
        case 0: W = w0; break; case 1: W = w1; break; case 2: W = w2; break;
        case 3: W = w3; break; case 4: W = w4; break; case 5: W = w5; break;
        case 6: W = w6; break; case 7: W = w7; break; default: W = w8; break;
    }
    unsigned short* out = wt + (size_t)blockIdx.z * 65536;
    __shared__ float fs[32][33];
    int tid = threadIdx.x;
    int bk = blockIdx.x * 32, bn = blockIdx.y * 32;
    int k = tid >> 3, n4 = (tid & 7) * 4;
    float4 v = *(const float4*)&W[(size_t)(bk + k) * 256 + bn + n4];
    fs[k][n4] = v.x; fs[k][n4 + 1] = v.y; fs[k][n4 + 2] = v.z; fs[k][n4 + 3] = v.w;
    __syncthreads();
    int n = tid >> 3, k4 = (tid & 7) * 4;
    ushort4 o;
    o.x = f2bf(fs[k4 + 0][n]); o.y = f2bf(fs[k4 + 1][n]);
    o.z = f2bf(fs[k4 + 2][n]); o.w = f2bf(fs[k4 + 3][n]);
    *(ushort4*)&out[(size_t)(bn + n) * 256 + bk + k4] = o;
}

// ---------------- MFMA GEMM: out = epi(A[M,256] @ W + bias (+resid)) ----------------
// A fp32 row-major; Wt bf16 [n][k]. Tile 64(M)x32(N), 4 waves each 16x32.
// EPI: 0 = fp32 [M][256] (+resid, ACT1 = exact gelu)
//      1 = bf16 [bh][tok][32] (value scaled by `scale`)   (Q/K layout)
//      2 = bf16 [bh][32][tok]                             (V^T layout)
template<int EPI, int ACT>
__global__ __launch_bounds__(256) void k_gemm_mfma(const float* __restrict__ A,
    const unsigned short* __restrict__ Wt, const float* __restrict__ bias,
    const float* __restrict__ resid, void* __restrict__ outp, float scale)
{
    __shared__ unsigned short As[64][40];   // 32 k padded to 40 (2-way conflict = free)
    int tid = threadIdx.x;
    int w = tid >> 6, l = tid & 63;
    int l15 = l & 15, hi = l >> 4;
    int bm = blockIdx.x * 64, bn = blockIdx.y * 32;

    f32x4 acc0 = {0.f, 0.f, 0.f, 0.f};
    f32x4 acc1 = {0.f, 0.f, 0.f, 0.f};
    int r0 = tid >> 3, kq = (tid & 7) * 4;

    for (int kk = 0; kk < 256; kk += 32) {
        float4 a0 = *(const float4*)&A[(size_t)(bm + r0) * 256 + kk + kq];
        float4 a1 = *(const float4*)&A[(size_t)(bm + r0 + 32) * 256 + kk + kq];
        ushort4 u0, u1;
        u0.x = f2bf(a0.x); u0.y = f2bf(a0.y); u0.z = f2bf(a0.z); u0.w = f2bf(a0.w);
        u1.x = f2bf(a1.x); u1.y = f2bf(a1.y); u1.z = f2bf(a1.z); u1.w = f2bf(a1.w);
        *(ushort4*)&As[r0][kq] = u0;
        *(ushort4*)&As[r0 + 32][kq] = u1;
        __syncthreads();
        // A-frag: row = w*16 + l15, k = hi*8+e (contig)
        bf16x8 af = *(const bf16x8*)&As[w * 16 + l15][hi * 8];
        // B-frags direct from global (L2-resident): col = l15 (+16), k contig
        bf16x8 b0 = *(const bf16x8*)&Wt[(size_t)(bn + l15) * 256 + kk + hi * 8];
        bf16x8 b1 = *(const bf16x8*)&Wt[(size_t)(bn + 16 + l15) * 256 + kk + hi * 8];
        acc0 = __builtin_amdgcn_mfma_f32_16x16x32_bf16(af, b0, acc0, 0, 0, 0);
        acc1 = __builtin_amdgcn_mfma_f32_16x16x32_bf16(af, b1, acc1, 0, 0, 0);
        __syncthreads();
    }

    float* outf = (float*)outp;
    unsigned short* outb = (unsigned short*)outp;
    #pragma unroll
    for (int j = 0; j < 2; j++) {
        #pragma unroll
        for (int r = 0; r < 4; r++) {
            float vv = (j == 0) ? acc0[r] : acc1[r];
            int gcol = bn + j * 16 + l15;
            int grow = bm + w * 16 + hi * 4 + r;   // C: col=lane&15, row=4*(l>>4)+reg
            if (bias) vv += bias[gcol];
            if (EPI == 0) {
                if (resid) vv += resid[(size_t)grow * 256 + gcol];
                if (ACT == 1) vv = 0.5f * vv * (1.f + erff(vv * 0.70710678118654752f));
                outf[(size_t)grow * 256 + gcol] = vv;
            } else {
                int b = grow >= NTOK;
                int tok = grow - b * NTOK;
                int h = gcol >> 5, d = gcol & 31;
                if (EPI == 1)
                    outb[(((size_t)(b * 8 + h)) * NTOK + tok) * 32 + d] = f2bf(vv * scale);
                else
                    outb[((size_t)(b * 8 + h) * 32 + d) * NTOK + tok] = f2bf(vv);
            }
        }
    }
}

// ---------------- MFMA flash attention ----------------
// block: 16 queries, 4 waves split the 2304 keys (576 each).
// q pre-scaled by (1/sqrt(dh))*log2(e) -> softmax in exp2 domain.
// Per 32-key step: S^T = mfma(K,Qt) x2; online softmax (keys lane-local,
// defer-rescale); P packed via v_cvt_pk_bf16_f32 and transposed through
// per-wave LDS (2x ds_write_b64 + ds_read_b128); O^T += mfma(V^T, P) x2.
__global__ __launch_bounds__(256) void k_attn_mfma(
    const unsigned short* __restrict__ qb, const unsigned short* __restrict__ kb,
    const unsigned short* __restrict__ vt, float* __restrict__ O)
{
    int bh = blockIdx.y; int b = bh >> 3, h = bh & 7;
    int tid = threadIdx.x;
    int w = tid >> 6, l = tid & 63;
    int q15 = l & 15, hi = l >> 4;
    int q0 = blockIdx.x * 16;

    bf16x8 qf = *(const bf16x8*)(qb + ((size_t)bh * NTOK + q0 + q15) * 32 + hi * 8);

    f32x4 cv0 = {0.f, 0.f, 0.f, 0.f};
    f32x4 cv1 = {0.f, 0.f, 0.f, 0.f};
    float mrun = -1e30f, lsum = 0.f;

    const unsigned short* kbh = kb + (size_t)bh * NTOK * 32;
    const unsigned short* vbh = vt + (size_t)bh * 32 * NTOK;
    int kstart = w * (NTOK / 4);

    // per-wave P transpose buffer: [16 q][40 k] bf16 (pad 32->40: 16B-aligned rows)
    __shared__ __align__(16) unsigned short plds[4][16 * 40];
    unsigned short* pl = plds[w];

    for (int kt = 0; kt < NTOK / 4; kt += 32) {
        int kbase = kstart + kt;
        bf16x8 kf0 = *(const bf16x8*)(kbh + (size_t)(kbase + q15) * 32 + hi * 8);
        bf16x8 kf1 = *(const bf16x8*)(kbh + (size_t)(kbase + 16 + q15) * 32 + hi * 8);
        f32x4 z = {0.f, 0.f, 0.f, 0.f};
        f32x4 s0 = __builtin_amdgcn_mfma_f32_16x16x32_bf16(kf0, qf, z, 0, 0, 0);
        f32x4 s1 = __builtin_amdgcn_mfma_f32_16x16x32_bf16(kf1, qf, z, 0, 0, 0);
        // lane holds S[q=q0+q15][keys kbase+4hi+r (s0), +16 (s1)]  (log2 units)

        // per-q tile max (reduce over hi groups)
        float mx = fmaxf(fmaxf(fmaxf(s0[0], s0[1]), fmaxf(s0[2], s0[3])),
                         fmaxf(fmaxf(s1[0], s1[1]), fmaxf(s1[2], s1[3])));
        mx = fmaxf(mx, __shfl_xor(mx, 16, 64));
        mx = fmaxf(mx, __shfl_xor(mx, 32, 64));

        // defer-rescale: only when a new max appears anywhere in the wave
        if (__any(mx > mrun)) {
            float mnew = fmaxf(mrun, mx);
            float corr = EXP2F(mrun - mnew);
            mrun = mnew;
            lsum *= corr;
            cv0 *= corr; cv1 *= corr;
        }

        float p0[4], p1[4];
        #pragma unroll
        for (int r = 0; r < 4; r++) {
            p0[r] = EXP2F(s0[r] - mrun);
            p1[r] = EXP2F(s1[r] - mrun);
            lsum += p0[r] + p1[r];
        }

        // pack P to bf16 pairs (HW pack) and transpose via per-wave LDS
        unsigned int P0, P1, Q0, Q1;
        asm("v_cvt_pk_bf16_f32 %0, %1, %2" : "=v"(P0) : "v"(p0[0]), "v"(p0[1]));
        asm("v_cvt_pk_bf16_f32 %0, %1, %2" : "=v"(P1) : "v"(p0[2]), "v"(p0[3]));
        asm("v_cvt_pk_bf16_f32 %0, %1, %2" : "=v"(Q0) : "v"(p1[0]), "v"(p1[1]));
        asm("v_cvt_pk_bf16_f32 %0, %1, %2" : "=v"(Q1) : "v"(p1[2]), "v"(p1[3]));
        uint2 w0; w0.x = P0; w0.y = P1;
        uint2 w1; w1.x = Q0; w1.y = Q1;
        *(uint2*)(pl + q15 * 40 + hi * 4)      = w0;   // keys 4hi..4hi+3
        *(uint2*)(pl + q15 * 40 + 16 + hi * 4) = w1;   // keys 16+4hi..+3
        // same wave reads back (compiler inserts lgkmcnt wait; no barrier needed)
        bf16x8 pf = *(const bf16x8*)(pl + q15 * 40 + hi * 8);  // P[q][k=8hi+e]

        bf16x8 v0 = *(const bf16x8*)(vbh + (size_t)q15 * NTOK + kbase + hi * 8);
        bf16x8 v1 = *(const bf16x8*)(vbh + (size_t)(q15 + 16) * NTOK + kbase + hi * 8);

        cv0 = __builtin_amdgcn_mfma_f32_16x16x32_bf16(v0, pf, cv0, 0, 0, 0);
        cv1 = __builtin_amdgcn_mfma_f32_16x16x32_bf16(v1, pf, cv1, 0, 0, 0);
    }

    // finalize per-lane partial l: reduce over hi groups once
    lsum += __shfl_xor(lsum, 16, 64);
    lsum += __shfl_xor(lsum, 32, 64);

    // merge the 4 key-split partials via LDS
    __shared__ float lm[4][16], ll[4][16];
    __shared__ float lo[4][16][32];
    if (hi == 0) { lm[w][q15] = mrun; ll[w][q15] = lsum; }
    #pragma unroll
    for (int r = 0; r < 4; r++) {
        lo[w][q15][hi * 4 + r]      = cv0[r];
        lo[w][q15][16 + hi * 4 + r] = cv1[r];
    }
    __syncthreads();

    int q = tid >> 4;
    int d0 = (tid & 15) * 2;
    float M = fmaxf(fmaxf(lm[0][q], lm[1][q]), fmaxf(lm[2][q], lm[3][q]));
    float wgt[4]; float L = 0.f;
    #pragma unroll
    for (int s = 0; s < 4; s++) { wgt[s] = EXP2F(lm[s][q] - M); L += ll[s][q] * wgt[s]; }
    float invL = 1.f / L;
    float2 o2;
    o2.x = (lo[0][q][d0]     * wgt[0] + lo[1][q][d0]     * wgt[1]
          + lo[2][q][d0]     * wgt[2] + lo[3][q][d0]     * wgt[3]) * invL;
    o2.y = (lo[0][q][d0 + 1] * wgt[0] + lo[1][q][d0 + 1] * wgt[1]
          + lo[2][q][d0 + 1] * wgt[2] + lo[3][q][d0 + 1] * wgt[3]) * invL;
    *(float2*)&O[((size_t)(b * NTOK + q0 + q)) * 256 + h * 32 + d0] = o2;
}

// ---------------- GAT pieces ----------------

__global__ __launch_bounds__(256) void k_attvec(const float* __restrict__ h,
    const float* __restrict__ wsrc, const float* __restrict__ wdst,
    float* __restrict__ a_src, float* __restrict__ a_dst)
{
    int node = blockIdx.x;
    int c = threadIdx.x;
    float hv = h[(size_t)node * CH + c];
    __shared__ float s1[4], s2[4];
    float a = hv * wsrc[c], q = hv * wdst[c];
    red2(a, q, s1, s2);
    if (c == 0) { a_src[node] = a; a_dst[node] = q; }
}

__global__ void k_fill_edges(const int* __restrict__ ei, int Eed,
    int* __restrict__ deg, int* __restrict__ csr)
{
    int e = blockIdx.x * 256 + threadIdx.x;
    if (e >= Eed) return;
    int src = ei[e];
    int dst = ei[Eed + e];
    int pos = atomicAdd(&deg[dst], 1);
    if (pos < 16) csr[dst * 16 + pos] = src;
}

__global__ __launch_bounds__(256) void k_gat_agg(const int* __restrict__ deg,
    const int* __restrict__ csr, const float* __restrict__ a_src,
    const float* __restrict__ a_dst, const float* __restrict__ h,
    const float* __restrict__ gbias, float* __restrict__ nf)
{
    int dst = blockIdx.x;
    int t = threadIdx.x;
    __shared__ float logit[16];
    __shared__ float alpha[16];
    __shared__ int srcs[16];
    int cnt = deg[dst]; if (cnt > 16) cnt = 16;
    if (t < cnt) {
        int s = csr[dst * 16 + t];
        srcs[t] = s;
        float lg = a_src[s] + a_dst[dst];
        logit[t] = lg > 0.f ? lg : 0.2f * lg;
    }
    __syncthreads();
    if (t == 0) {
        float mx = -1e30f;
        for (int i = 0; i < cnt; i++) mx = fmaxf(mx, logit[i]);
        float dn = 0.f;
        for (int i = 0; i < cnt; i++) { float ex = __expf(logit[i] - mx); alpha[i] = ex; dn += ex; }
        float inv = 1.f / (dn + 1e-16f);
        for (int i = 0; i < cnt; i++) alpha[i] *= inv;
    }
    __syncthreads();
    float accv = 0.f;
    for (int i = 0; i < cnt; i++) accv += alpha[i] * h[(size_t)srcs[i] * CH + t];
    float val = accv + gbias[t];
    val = val > 0.f ? val : expm1f(val);
    nf[(size_t)dst * CH + t] += val;
}

// ---------------- orchestration ----------------
extern "C" void kernel_launch(void* const* d_in, const int* in_sizes, int n_in,
                              void* d_out, int out_size, void* d_ws, size_t ws_size,
                              hipStream_t stream)
{
    const float* x_cnn   = (const float*)d_in[0];
    const int*   edge    = (const int*)d_in[1];
    const float* norm1_g = (const float*)d_in[2];
    const float* norm1_b = (const float*)d_in[3];
    const float* proj_w  = (const float*)d_in[4];
    const float* proj_b  = (const float*)d_in[5];
    const float* wq      = (const float*)d_in[6];
    const float* bq      = (const float*)d_in[7];
    const float* wk      = (const float*)d_in[8];
    const float* bk      = (const float*)d_in[9];
    const float* wv      = (const float*)d_in[10];
    const float* bv      = (const float*)d_in[11];
    const float* wo      = (const float*)d_in[12];
    const float* bo      = (const float*)d_in[13];
    const float* norm2_g = (const float*)d_in[14];
    const float* norm2_b = (const float*)d_in[15];
    const float* gpl_w   = (const float*)d_in[16];
    const float* gpl_b   = (const float*)d_in[17];
    const float* gat_w   = (const float*)d_in[18];
    const float* att_src = (const float*)d_in[19];
    const float* att_dst = (const float*)d_in[20];
    const float* gat_bias= (const float*)d_in[21];
    const float* norm3_g = (const float*)d_in[22];
    const float* norm3_b = (const float*)d_in[23];
    const float* mlp_w1  = (const float*)d_in[24];
    const float* mlp_b1  = (const float*)d_in[25];
    const float* mlp_w2  = (const float*)d_in[26];
    const float* mlp_b2  = (const float*)d_in[27];
    const float* fn_g    = (const float*)d_in[28];
    const float* fn_b    = (const float*)d_in[29];

    int Eed = in_sizes[1] / 2;
    float* out = (float*)d_out;

    const size_t NB = (size_t)NS * CH;   // 1,179,648
    float* ws   = (float*)d_ws;
    float* bufA = ws + 0 * NB;
    float* bufB = ws + 1 * NB;
    float* bufC = ws + 2 * NB;
    float* bufD = ws + 3 * NB;
    float* bufE = ws + 4 * NB;
    float* a_src = ws + 5 * NB;
    float* a_dst = a_src + NS;
    int*   deg   = (int*)(a_dst + NS);
    int*   csr   = deg + NS;             // NS*16 ints
    unsigned short* qb = (unsigned short*)(csr + (size_t)NS * 16);
    unsigned short* kb = qb + NB;
    unsigned short* vt = kb + NB;
    unsigned short* wt = vt + NB;        // 9 * 65536 bf16 transposed weights
    // total ws ≈ 33 MB

    // fold 1/sqrt(dh) AND log2(e) into q so softmax runs in exp2 domain
    const float qscale = 0.17677669529663687f * 1.4426950408889634f;
    dim3 gg(72, 8);       // 64x32 tiles over 4608x256
    dim3 gw(8, 8, 9);

    // 0. transpose+convert all weights to bf16 [n][k]
    k_wprep<<<gw, 256, 0, stream>>>(proj_w, wq, wk, wv, wo, gpl_w, gat_w,
                                    mlp_w1, mlp_w2, wt);
    // 1. tokenize + LN1 -> bufA
    k_ln_tok<<<NS, 256, 0, stream>>>(x_cnn, norm1_g, norm1_b, bufA);
    // 2. xv = bufA @ proj + proj_b -> bufB (fp32)
    k_gemm_mfma<0,0><<<gg, 256, 0, stream>>>(bufA, wt + 0 * 65536, proj_b, nullptr, bufB, 1.f);
    // 3. q,k (bf16 attn layout, q scaled), v (bf16 transposed)
    k_gemm_mfma<1,0><<<gg, 256, 0, stream>>>(bufB, wt + 1 * 65536, bq, nullptr, qb, qscale);
    k_gemm_mfma<1,0><<<gg, 256, 0, stream>>>(bufB, wt + 2 * 65536, bk, nullptr, kb, 1.f);
    k_gemm_mfma<2,0><<<gg, 256, 0, stream>>>(bufB, wt + 3 * 65536, bv, nullptr, vt, 1.f);
    // 4. MFMA flash attention -> bufA
    k_attn_mfma<<<dim3(144, 16), 256, 0, stream>>>(qb, kb, vt, bufA);
    // 5. nf = bufB + bufA @ wo + bo  (in-place into bufB)
    k_gemm_mfma<0,0><<<gg, 256, 0, stream>>>(bufA, wt + 4 * 65536, bo, bufB, bufB, 1.f);
    // 6. ln2 -> bufC
    k_ln<<<NS, 256, 0, stream>>>(bufB, norm2_g, norm2_b, bufC);
    // 7. xg = bufC @ gpl_w + gpl_b -> bufD
    k_gemm_mfma<0,0><<<gg, 256, 0, stream>>>(bufC, wt + 5 * 65536, gpl_b, nullptr, bufD, 1.f);
    // 8. h = bufD @ gat_w -> bufE
    k_gemm_mfma<0,0><<<gg, 256, 0, stream>>>(bufD, wt + 6 * 65536, nullptr, nullptr, bufE, 1.f);
    // 9. a_src/a_dst
    k_attvec<<<NS, 256, 0, stream>>>(bufE, att_src, att_dst, a_src, a_dst);
    // 10. CSR build
    (void)hipMemsetAsync(deg, 0, NS * sizeof(int), stream);
    k_fill_edges<<<(Eed + 255) / 256, 256, 0, stream>>>(edge, Eed, deg, csr);
    // 11. GAT aggregate + elu + residual (bufB updated in place)
    k_gat_agg<<<NS, 256, 0, stream>>>(deg, csr, a_src, a_dst, bufE, gat_bias, bufB);
    // 12. ln3 -> bufC
    k_ln<<<NS, 256, 0, stream>>>(bufB, norm3_g, norm3_b, bufC);
    // 13. mlp1 = gelu(bufC @ mlp_w1 + b1) -> bufD
    k_gemm_mfma<0,1><<<gg, 256, 0, stream>>>(bufC, wt + 7 * 65536, mlp_b1, nullptr, bufD, 1.f);
    // 14. y_pre = bufC + bufD @ mlp_w2 + b2 -> bufA
    k_gemm_mfma<0,0><<<gg, 256, 0, stream>>>(bufD, wt + 8 * 65536, mlp_b2, bufC, bufA, 1.f);
    // 15. final LN + transpose -> out
    k_ln_out<<<NS, 256, 0, stream>>>(bufA, fn_g, fn_b, out);
}